// Round 6
// baseline (141.081 us; speedup 1.0000x reference)
//
#include <hip/hip_runtime.h>
#include <math.h>

#define BB 4
#define NN 1024
#define HH 8
#define NROW (BB*NN)  // 4096

typedef short s8v __attribute__((ext_vector_type(8)));
typedef float f4v __attribute__((ext_vector_type(4)));

__device__ __forceinline__ short bf16rne(float f) {
    unsigned u = __float_as_uint(f);
    u += 0x7FFF + ((u >> 16) & 1u);
    return (short)(u >> 16);
}
__device__ __forceinline__ unsigned pk2(float a, float b) {
    return ((unsigned)(unsigned short)bf16rne(a)) |
           (((unsigned)(unsigned short)bf16rne(b)) << 16);
}

// ---------------------------------------------------------------------------
// K1: g = h@W (8 rows/block, 512 blocks).  [R2 verbatim minus Dt zeroing]
//  - Writes Gt = bf16(g) directly (unnormalized; per-j softmax 1/D applied in
//    k_out staging — softmax is over axis i so D depends only on (b,j,h)).
//  - Exp tables for the separable-max trick:
//      exp(lrelu(ei+ej)) == max(exp(ei)*exp(ej), exp(.2ei)*exp(.2ej))
// ---------------------------------------------------------------------------
__global__ __launch_bounds__(256) void k_gemm_ei(const float* __restrict__ hm,
                                                 const float* __restrict__ W,
                                                 const float* __restrict__ aw,
                                                 short* __restrict__ Gt,
                                                 float* __restrict__ EFi,
                                                 float* __restrict__ EFjt) {
    __shared__ __align__(16) float hs[8][256];
    __shared__ float aws[64];
    const int row0 = blockIdx.x * 8;
    const int t = threadIdx.x;
    if (t < 64) aws[t] = aw[t];
    const float4* h4 = (const float4*)(hm + row0 * 256);
    float4* hs4 = (float4*)&hs[0][0];
    hs4[t] = h4[t];
    hs4[t + 256] = h4[t + 256];
    __syncthreads();

    float acc[8];
#pragma unroll
    for (int r = 0; r < 8; ++r) acc[r] = 0.f;
    for (int k4 = 0; k4 < 64; ++k4) {
        const float w0 = W[(4 * k4 + 0) * 256 + t];
        const float w1 = W[(4 * k4 + 1) * 256 + t];
        const float w2 = W[(4 * k4 + 2) * 256 + t];
        const float w3 = W[(4 * k4 + 3) * 256 + t];
#pragma unroll
        for (int r = 0; r < 8; ++r) {
            const float4 hv = *(const float4*)&hs[r][4 * k4];  // broadcast read
            acc[r] = fmaf(hv.x, w0, acc[r]);
            acc[r] = fmaf(hv.y, w1, acc[r]);
            acc[r] = fmaf(hv.z, w2, acc[r]);
            acc[r] = fmaf(hv.w, w3, acc[r]);
        }
    }
    const int d = t & 31, hh = t >> 5;
    const int b = row0 >> 10;

    // ---- Gt[b][h][jt(32)][d(32)][jj(32)] = bf16(g), 8 consecutive j per thread
    {
        const int n0 = row0 & (NN - 1);
        short* dst = Gt + ((size_t)((b * 8 + hh) * 32 + (n0 >> 5))) * 1024 +
                     d * 32 + (n0 & 31);
        uint4 w;
        w.x = pk2(acc[0], acc[1]);
        w.y = pk2(acc[2], acc[3]);
        w.z = pk2(acc[4], acc[5]);
        w.w = pk2(acc[6], acc[7]);
        *(uint4*)dst = w;
    }

    // ---- e_i / e_j exp tables
#pragma unroll
    for (int r = 0; r < 8; ++r) {
        float vi = acc[r] * aws[d];
        float vj = acc[r] * aws[32 + d];
#pragma unroll
        for (int mm = 1; mm < 32; mm <<= 1) {
            vi += __shfl_xor(vi, mm);
            vj += __shfl_xor(vj, mm);
        }
        if (d == 0) {
            const int row = row0 + r;
            const int n = row & (NN - 1);
            *(float2*)&EFi[(size_t)row * 16 + hh * 2] =
                make_float2(__expf(vi), __expf(0.2f * vi));
            EFjt[((size_t)(b * 8 + hh) * 2 + 0) * NN + n] = __expf(vj);
            EFjt[((size_t)(b * 8 + hh) * 2 + 1) * NN + n] = __expf(0.2f * vj);
        }
    }
}

// ---------------------------------------------------------------------------
// K2: denominator partials. [R2's k_den verbatim, atomic REMOVED — replaced
// by a plain store of this i-chunk's partial to ps[ic][b][h][j]; k_out sums
// the 8 chunks at staging time. Deterministic, no unsafeAtomicAdd (whose
// silent-drop-on-fine-grained-memory hazard is the prime NaN suspect for
// R3-R5's environment-dependent failures).]
// 512 blocks = b x 16 j-chunks x 8 i-chunks.
// ---------------------------------------------------------------------------
__global__ __launch_bounds__(256) void k_s(const float* __restrict__ adj,
                                           const float* __restrict__ EFi,
                                           const float* __restrict__ EFjt,
                                           float* __restrict__ ps) {
    __shared__ __align__(16) float eis[128 * 16];  // 8KB: {E,F} x 8h per i
    __shared__ float sp[4][8][64];
    const int bx = blockIdx.x;
    const int b = bx >> 7, jc = (bx >> 3) & 15, ic = bx & 7;
    const int j0 = jc * 64, i0 = ic * 128;
    const int t = threadIdx.x;

    const float4* src4 = (const float4*)(EFi + (size_t)(b * NN + i0) * 16);
    ((float4*)eis)[t] = src4[t];
    ((float4*)eis)[t + 256] = src4[t + 256];

    const int ii = t >> 6, jj = t & 63;
    // per-thread E/F for its j column, all 8 heads (coalesced rows of EFjt)
    const float* ejb = EFjt + (size_t)b * 16 * NN + j0 + jj;
    const float ejE0 = ejb[0 * NN],  ejF0 = ejb[1 * NN];
    const float ejE1 = ejb[2 * NN],  ejF1 = ejb[3 * NN];
    const float ejE2 = ejb[4 * NN],  ejF2 = ejb[5 * NN];
    const float ejE3 = ejb[6 * NN],  ejF3 = ejb[7 * NN];
    const float ejE4 = ejb[8 * NN],  ejF4 = ejb[9 * NN];
    const float ejE5 = ejb[10 * NN], ejF5 = ejb[11 * NN];
    const float ejE6 = ejb[12 * NN], ejF6 = ejb[13 * NN];
    const float ejE7 = ejb[14 * NN], ejF7 = ejb[15 * NN];
    __syncthreads();

    float s0 = 0.f, s1 = 0.f, s2 = 0.f, s3 = 0.f;
    float s4 = 0.f, s5 = 0.f, s6 = 0.f, s7 = 0.f;
    const float* adjp = adj + (size_t)b * NN * NN + j0 + jj;
    for (int i = ii; i < 128; i += 4) {
        const float a = adjp[(size_t)(i0 + i) * NN];
        const float4 x0 = *(const float4*)&eis[i * 16];      // broadcast reads
        const float4 x1 = *(const float4*)&eis[i * 16 + 4];
        const float4 x2 = *(const float4*)&eis[i * 16 + 8];
        const float4 x3 = *(const float4*)&eis[i * 16 + 12];
        s0 = fmaf(a, fmaxf(x0.x * ejE0, x0.y * ejF0), s0);
        s1 = fmaf(a, fmaxf(x0.z * ejE1, x0.w * ejF1), s1);
        s2 = fmaf(a, fmaxf(x1.x * ejE2, x1.y * ejF2), s2);
        s3 = fmaf(a, fmaxf(x1.z * ejE3, x1.w * ejF3), s3);
        s4 = fmaf(a, fmaxf(x2.x * ejE4, x2.y * ejF4), s4);
        s5 = fmaf(a, fmaxf(x2.z * ejE5, x2.w * ejF5), s5);
        s6 = fmaf(a, fmaxf(x3.x * ejE6, x3.y * ejF6), s6);
        s7 = fmaf(a, fmaxf(x3.z * ejE7, x3.w * ejF7), s7);
    }
    sp[ii][0][jj] = s0; sp[ii][1][jj] = s1; sp[ii][2][jj] = s2; sp[ii][3][jj] = s3;
    sp[ii][4][jj] = s4; sp[ii][5][jj] = s5; sp[ii][6][jj] = s6; sp[ii][7][jj] = s7;
    __syncthreads();
#pragma unroll
    for (int k = 0; k < 2; ++k) {
        const int idx = t * 2 + k;
        const int jjo = idx >> 3, hq = idx & 7;
        const float sv =
            sp[0][hq][jjo] + sp[1][hq][jjo] + sp[2][hq][jjo] + sp[3][hq][jjo];
        // transposed partials: ps[ic][b][h][j]
        ps[((size_t)(ic * 4 + b) * 8 + hq) * 1024 + j0 + jjo] = sv;
    }
}

// ---------------------------------------------------------------------------
// K3: MFMA contraction. [R2 verbatim schedule, NO setprio] 512 blocks =
// (h-half, b, i-tile16); 4 waves, 1 head each.
//   A[i,j] = adj * max(Ei*(Ej/D), Fi*(Fj/D)) built in registers in A-frag
//   layout (m=lane&15, k=quad*8+e); packed via v_cvt_pk_bf16_f32.
// ONLY delta vs R2: dv is now the sum of 8 i-chunk partials from ps
// (8 coalesced L2-resident float4 loads, issued at the same program point
// as R2's single Dt load). No atomics anywhere in the pipeline.
// ---------------------------------------------------------------------------
__global__ __launch_bounds__(256) void k_out_mfma(const float* __restrict__ adj,
                                                  const short* __restrict__ Gt,
                                                  const float* __restrict__ EFi,
                                                  const float* __restrict__ EFjt,
                                                  const float* __restrict__ ps,
                                                  float* __restrict__ out) {
    __shared__ short gts[4][4][32][40];  // 40KB: [h-local][jt-local][d][jj+pad]
    __shared__ float ejt[4][2][128];     // 4KB: [h-local][{E,F}/D][j in superstep]
    const int bx = blockIdx.x;
    const int hs = bx >> 8, b = (bx >> 6) & 3, i0 = (bx & 63) * 16;
    const int t = threadIdx.x;
    const int wave = t >> 6, lane = t & 63;
    const int m = lane & 15, q = lane >> 4;
    const int h = hs * 4 + wave;  // this wave's head

    const float2 eif = *(const float2*)&EFi[(size_t)(b * NN + i0 + m) * 16 + h * 2];
    const float EiV = eif.x, FiV = eif.y;
    f4v acc0 = {0.f, 0.f, 0.f, 0.f}, acc1 = {0.f, 0.f, 0.f, 0.f};

    const float* adjrow = adj + (size_t)b * NN * NN + (size_t)(i0 + m) * NN;
    const float4* gtg4 = (const float4*)Gt;  // 8 shorts per float4
    const float4* ejt4 = (const float4*)(EFjt + (size_t)b * 8 * 2 * NN);
    const f4v* psv = (const f4v*)ps;  // [ic][b][h][j/4], ic stride 8192 f4

    for (int s = 0; s < 8; ++s) {
        // ---- issue Gt loads (named regs g0..g7) + adj loads (a0..a7) + ej
        float4 g0, g1, g2, g3, g4, g5, g6, g7;
#define LG(k)                                                                     \
        {                                                                         \
            const int u = t + 256 * (k);                                          \
            g##k = gtg4[(size_t)(b * 8 + hs * 4 + (u >> 9)) * 4096 + s * 512 +    \
                        (u & 511)];                                               \
        }
        LG(0) LG(1) LG(2) LG(3) LG(4) LG(5) LG(6) LG(7)
#undef LG
        f4v a0, a1, a2, a3, a4, a5, a6, a7;
#define LA(k2, lt, half)                                                          \
        a##k2 = *(const f4v*)&adjrow[s * 128 + (lt) * 32 + q * 8 + (half) * 4];
        LA(0, 0, 0) LA(1, 0, 1) LA(2, 1, 0) LA(3, 1, 1)
        LA(4, 2, 0) LA(5, 2, 1) LA(6, 3, 0) LA(7, 3, 1)
#undef LA
        // all 256 threads: one float4 of EFjt ({E,F} rows x 4 heads x 32 f4),
        // scaled by the per-(j,h) softmax denominator = sum of 8 ps chunks.
        float4 ev =
            ejt4[(size_t)((hs * 4 + (t >> 6)) * 2 + ((t >> 5) & 1)) * 256 +
                 s * 32 + (t & 31)];
        {
            const size_t pbase =
                ((size_t)b * 8 + (hs * 4 + (t >> 6))) * 256 + s * 32 + (t & 31);
            const f4v dva = psv[pbase]              + psv[pbase + 1 * 8192] +
                            psv[pbase + 2 * 8192]   + psv[pbase + 3 * 8192] +
                            psv[pbase + 4 * 8192]   + psv[pbase + 5 * 8192] +
                            psv[pbase + 6 * 8192]   + psv[pbase + 7 * 8192];
            ev.x /= dva[0]; ev.y /= dva[1]; ev.z /= dva[2]; ev.w /= dva[3];
        }
        __syncthreads();  // prior super's LDS reads done
#define SG(k)                                                                     \
        {                                                                         \
            const int u = t + 256 * (k);                                          \
            char* dstp = (char*)gts + (u >> 9) * 10240 + ((u >> 7) & 3) * 2560 +  \
                         ((u >> 2) & 31) * 80 + (u & 3) * 16;                     \
            *(float4*)dstp = g##k;                                                \
        }
        SG(0) SG(1) SG(2) SG(3) SG(4) SG(5) SG(6) SG(7)
#undef SG
        *(float4*)&ejt[t >> 6][(t >> 5) & 1][(t & 31) * 4] = ev;
        __syncthreads();  // LDS tile visible

        // ---- compute: 4 j-steps of 32, A built in named regs only
#define LT(lt, aA, aB)                                                            \
        {                                                                         \
            const f4v ejA = *(const f4v*)&ejt[wave][0][(lt) * 32 + q * 8];        \
            const f4v ejB = *(const f4v*)&ejt[wave][0][(lt) * 32 + q * 8 + 4];    \
            const f4v fjA = *(const f4v*)&ejt[wave][1][(lt) * 32 + q * 8];        \
            const f4v fjB = *(const f4v*)&ejt[wave][1][(lt) * 32 + q * 8 + 4];    \
            const float p0 = aA[0] * fmaxf(EiV * ejA[0], FiV * fjA[0]);           \
            const float p1 = aA[1] * fmaxf(EiV * ejA[1], FiV * fjA[1]);           \
            const float p2 = aA[2] * fmaxf(EiV * ejA[2], FiV * fjA[2]);           \
            const float p3 = aA[3] * fmaxf(EiV * ejA[3], FiV * fjA[3]);           \
            const float p4 = aB[0] * fmaxf(EiV * ejB[0], FiV * fjB[0]);           \
            const float p5 = aB[1] * fmaxf(EiV * ejB[1], FiV * fjB[1]);           \
            const float p6 = aB[2] * fmaxf(EiV * ejB[2], FiV * fjB[2]);           \
            const float p7 = aB[3] * fmaxf(EiV * ejB[3], FiV * fjB[3]);           \
            unsigned w0, w1, w2, w3;                                              \
            asm("v_cvt_pk_bf16_f32 %0, %1, %2" : "=v"(w0) : "v"(p0), "v"(p1));    \
            asm("v_cvt_pk_bf16_f32 %0, %1, %2" : "=v"(w1) : "v"(p2), "v"(p3));    \
            asm("v_cvt_pk_bf16_f32 %0, %1, %2" : "=v"(w2) : "v"(p4), "v"(p5));    \
            asm("v_cvt_pk_bf16_f32 %0, %1, %2" : "=v"(w3) : "v"(p6), "v"(p7));    \
            union { unsigned u[4]; s8v v; } Au;                                   \
            Au.u[0] = w0; Au.u[1] = w1; Au.u[2] = w2; Au.u[3] = w3;               \
            const s8v A = Au.v;                                                   \
            const s8v B0 = *(const s8v*)&gts[wave][lt][m][q * 8];                 \
            const s8v B1 = *(const s8v*)&gts[wave][lt][m + 16][q * 8];            \
            acc0 = __builtin_amdgcn_mfma_f32_16x16x32_bf16(A, B0, acc0, 0, 0, 0); \
            acc1 = __builtin_amdgcn_mfma_f32_16x16x32_bf16(A, B1, acc1, 0, 0, 0); \
        }
        LT(0, a0, a1) LT(1, a2, a3) LT(2, a4, a5) LT(3, a6, a7)
#undef LT
    }

    // ---- epilogue: C layout col=lane&15, row=quad*4+reg (already normalized)
    float* op = out + (size_t)(b * NN + i0) * 256;
#pragma unroll
    for (int r = 0; r < 4; ++r) {
        const int row = q * 4 + r;
        op[(size_t)row * 256 + h * 32 + m] = acc0[r];
        op[(size_t)row * 256 + h * 32 + 16 + m] = acc1[r];
    }
}

// ---------------------------------------------------------------------------
extern "C" void kernel_launch(void* const* d_in, const int* in_sizes, int n_in,
                              void* d_out, int out_size, void* d_ws, size_t ws_size,
                              hipStream_t stream) {
    const float* h      = (const float*)d_in[0];  // [4,1024,256]
    const float* adj    = (const float*)d_in[1];  // [4,1024,1024,1]
    const float* W      = (const float*)d_in[2];  // [256,256]
    const float* attn_w = (const float*)d_in[3];  // [64]
    float* out = (float*)d_out;                   // [4,1024,256]

    float* ws = (float*)d_ws;
    short* Gt   = (short*)ws;              // 1,048,576 shorts used (4MB slot)
    float* EFi  = ws + 1048576;            // 65,536 f
    float* EFjt = EFi + NROW * 16;         // 65,536 f  [b][h][{E,F}][n]
    float* ps   = EFjt + NROW * 16;        // 262,144 f [ic][b][h][j]

    k_gemm_ei<<<NROW / 8, 256, 0, stream>>>(h, W, attn_w, Gt, EFi, EFjt);
    k_s<<<512, 256, 0, stream>>>(adj, EFi, EFjt, ps);
    k_out_mfma<<<512, 256, 0, stream>>>(adj, Gt, EFi, EFjt, ps, out);
}

// Round 7
// 123.629 us; speedup vs baseline: 1.1412x; 1.1412x over previous
//
#include <hip/hip_runtime.h>
#include <math.h>

#define BB 4
#define NN 1024
#define HH 8
#define NROW (BB*NN)  // 4096

typedef short s8v __attribute__((ext_vector_type(8)));
typedef float f4v __attribute__((ext_vector_type(4)));

__device__ __forceinline__ short bf16rne(float f) {
    unsigned u = __float_as_uint(f);
    u += 0x7FFF + ((u >> 16) & 1u);
    return (short)(u >> 16);
}
__device__ __forceinline__ unsigned pk2(float a, float b) {
    return ((unsigned)(unsigned short)bf16rne(a)) |
           (((unsigned)(unsigned short)bf16rne(b)) << 16);
}

// ---------------------------------------------------------------------------
// K1: g = h@W (8 rows/block, 512 blocks).  [R6 verbatim — passing]
//  - Writes Gt = bf16(g) directly (unnormalized; per-j softmax 1/D applied via
//    pre-normalized EFjtn — softmax is over axis i so D depends only on (b,j,h)).
//  - Exp tables for the separable-max trick:
//      exp(lrelu(ei+ej)) == max(exp(ei)*exp(ej), exp(.2ei)*exp(.2ej))
// ---------------------------------------------------------------------------
__global__ __launch_bounds__(256) void k_gemm_ei(const float* __restrict__ hm,
                                                 const float* __restrict__ W,
                                                 const float* __restrict__ aw,
                                                 short* __restrict__ Gt,
                                                 float* __restrict__ EFi,
                                                 float* __restrict__ EFjt) {
    __shared__ __align__(16) float hs[8][256];
    __shared__ float aws[64];
    const int row0 = blockIdx.x * 8;
    const int t = threadIdx.x;
    if (t < 64) aws[t] = aw[t];
    const float4* h4 = (const float4*)(hm + row0 * 256);
    float4* hs4 = (float4*)&hs[0][0];
    hs4[t] = h4[t];
    hs4[t + 256] = h4[t + 256];
    __syncthreads();

    float acc[8];
#pragma unroll
    for (int r = 0; r < 8; ++r) acc[r] = 0.f;
    for (int k4 = 0; k4 < 64; ++k4) {
        const float w0 = W[(4 * k4 + 0) * 256 + t];
        const float w1 = W[(4 * k4 + 1) * 256 + t];
        const float w2 = W[(4 * k4 + 2) * 256 + t];
        const float w3 = W[(4 * k4 + 3) * 256 + t];
#pragma unroll
        for (int r = 0; r < 8; ++r) {
            const float4 hv = *(const float4*)&hs[r][4 * k4];  // broadcast read
            acc[r] = fmaf(hv.x, w0, acc[r]);
            acc[r] = fmaf(hv.y, w1, acc[r]);
            acc[r] = fmaf(hv.z, w2, acc[r]);
            acc[r] = fmaf(hv.w, w3, acc[r]);
        }
    }
    const int d = t & 31, hh = t >> 5;
    const int b = row0 >> 10;

    // ---- Gt[b][h][jt(32)][d(32)][jj(32)] = bf16(g), 8 consecutive j per thread
    {
        const int n0 = row0 & (NN - 1);
        short* dst = Gt + ((size_t)((b * 8 + hh) * 32 + (n0 >> 5))) * 1024 +
                     d * 32 + (n0 & 31);
        uint4 w;
        w.x = pk2(acc[0], acc[1]);
        w.y = pk2(acc[2], acc[3]);
        w.z = pk2(acc[4], acc[5]);
        w.w = pk2(acc[6], acc[7]);
        *(uint4*)dst = w;
    }

    // ---- e_i / e_j exp tables
#pragma unroll
    for (int r = 0; r < 8; ++r) {
        float vi = acc[r] * aws[d];
        float vj = acc[r] * aws[32 + d];
#pragma unroll
        for (int mm = 1; mm < 32; mm <<= 1) {
            vi += __shfl_xor(vi, mm);
            vj += __shfl_xor(vj, mm);
        }
        if (d == 0) {
            const int row = row0 + r;
            const int n = row & (NN - 1);
            *(float2*)&EFi[(size_t)row * 16 + hh * 2] =
                make_float2(__expf(vi), __expf(0.2f * vi));
            EFjt[((size_t)(b * 8 + hh) * 2 + 0) * NN + n] = __expf(vj);
            EFjt[((size_t)(b * 8 + hh) * 2 + 1) * NN + n] = __expf(0.2f * vj);
        }
    }
}

// ---------------------------------------------------------------------------
// K2: denominator partials ps[ic][b][h][j]. [R6 verbatim — passing]
// 512 blocks = b x 16 j-chunks x 8 i-chunks. Plain stores, no atomics.
// ---------------------------------------------------------------------------
__global__ __launch_bounds__(256) void k_s(const float* __restrict__ adj,
                                           const float* __restrict__ EFi,
                                           const float* __restrict__ EFjt,
                                           float* __restrict__ ps) {
    __shared__ __align__(16) float eis[128 * 16];  // 8KB: {E,F} x 8h per i
    __shared__ float sp[4][8][64];
    const int bx = blockIdx.x;
    const int b = bx >> 7, jc = (bx >> 3) & 15, ic = bx & 7;
    const int j0 = jc * 64, i0 = ic * 128;
    const int t = threadIdx.x;

    const float4* src4 = (const float4*)(EFi + (size_t)(b * NN + i0) * 16);
    ((float4*)eis)[t] = src4[t];
    ((float4*)eis)[t + 256] = src4[t + 256];

    const int ii = t >> 6, jj = t & 63;
    // per-thread E/F for its j column, all 8 heads (coalesced rows of EFjt)
    const float* ejb = EFjt + (size_t)b * 16 * NN + j0 + jj;
    const float ejE0 = ejb[0 * NN],  ejF0 = ejb[1 * NN];
    const float ejE1 = ejb[2 * NN],  ejF1 = ejb[3 * NN];
    const float ejE2 = ejb[4 * NN],  ejF2 = ejb[5 * NN];
    const float ejE3 = ejb[6 * NN],  ejF3 = ejb[7 * NN];
    const float ejE4 = ejb[8 * NN],  ejF4 = ejb[9 * NN];
    const float ejE5 = ejb[10 * NN], ejF5 = ejb[11 * NN];
    const float ejE6 = ejb[12 * NN], ejF6 = ejb[13 * NN];
    const float ejE7 = ejb[14 * NN], ejF7 = ejb[15 * NN];
    __syncthreads();

    float s0 = 0.f, s1 = 0.f, s2 = 0.f, s3 = 0.f;
    float s4 = 0.f, s5 = 0.f, s6 = 0.f, s7 = 0.f;
    const float* adjp = adj + (size_t)b * NN * NN + j0 + jj;
    for (int i = ii; i < 128; i += 4) {
        const float a = adjp[(size_t)(i0 + i) * NN];
        const float4 x0 = *(const float4*)&eis[i * 16];      // broadcast reads
        const float4 x1 = *(const float4*)&eis[i * 16 + 4];
        const float4 x2 = *(const float4*)&eis[i * 16 + 8];
        const float4 x3 = *(const float4*)&eis[i * 16 + 12];
        s0 = fmaf(a, fmaxf(x0.x * ejE0, x0.y * ejF0), s0);
        s1 = fmaf(a, fmaxf(x0.z * ejE1, x0.w * ejF1), s1);
        s2 = fmaf(a, fmaxf(x1.x * ejE2, x1.y * ejF2), s2);
        s3 = fmaf(a, fmaxf(x1.z * ejE3, x1.w * ejF3), s3);
        s4 = fmaf(a, fmaxf(x2.x * ejE4, x2.y * ejF4), s4);
        s5 = fmaf(a, fmaxf(x2.z * ejE5, x2.w * ejF5), s5);
        s6 = fmaf(a, fmaxf(x3.x * ejE6, x3.y * ejF6), s6);
        s7 = fmaf(a, fmaxf(x3.z * ejE7, x3.w * ejF7), s7);
    }
    sp[ii][0][jj] = s0; sp[ii][1][jj] = s1; sp[ii][2][jj] = s2; sp[ii][3][jj] = s3;
    sp[ii][4][jj] = s4; sp[ii][5][jj] = s5; sp[ii][6][jj] = s6; sp[ii][7][jj] = s7;
    __syncthreads();
#pragma unroll
    for (int k = 0; k < 2; ++k) {
        const int idx = t * 2 + k;
        const int jjo = idx >> 3, hq = idx & 7;
        const float sv =
            sp[0][hq][jjo] + sp[1][hq][jjo] + sp[2][hq][jjo] + sp[3][hq][jjo];
        // transposed partials: ps[ic][b][h][j]
        ps[((size_t)(ic * 4 + b) * 8 + hq) * 1024 + j0 + jjo] = sv;
    }
}

// ---------------------------------------------------------------------------
// K2b (NEW): hoisted normalization. D[b,h,j] = sum_ic ps; EFjtn = EFjt / D.
// 32 blocks x 256 threads, one float4 of j per thread. Removes the per-
// superstep 8-load ps-sum + divide chain from k_out (R6's +19us regression:
// 512 blocks x 8 supersteps redid this 2M times = 128MB L2 + serial rcp
// chain inside the latency-critical superstep). Done once: 1.8MB traffic.
// ---------------------------------------------------------------------------
__global__ __launch_bounds__(256) void k_nrm(const float* __restrict__ ps,
                                             const float* __restrict__ EFjt,
                                             float* __restrict__ EFjtn) {
    const int t = blockIdx.x * 256 + threadIdx.x;  // 0..8191 (f4 index)
    const f4v* p4 = (const f4v*)ps;  // [ic][bh][j4]: ic stride 8192, bh*256+j4 = t
    const f4v d = p4[t]            + p4[t + 1 * 8192] + p4[t + 2 * 8192] +
                  p4[t + 3 * 8192] + p4[t + 4 * 8192] + p4[t + 5 * 8192] +
                  p4[t + 6 * 8192] + p4[t + 7 * 8192];
    const int bh = t >> 8, j4 = t & 255;
    const f4v* e4 = (const f4v*)EFjt;   // [bh][half][j4]
    f4v* o4 = (f4v*)EFjtn;
    f4v E = e4[(size_t)(bh * 2 + 0) * 256 + j4];
    f4v F = e4[(size_t)(bh * 2 + 1) * 256 + j4];
    E[0] /= d[0]; E[1] /= d[1]; E[2] /= d[2]; E[3] /= d[3];
    F[0] /= d[0]; F[1] /= d[1]; F[2] /= d[2]; F[3] /= d[3];
    o4[(size_t)(bh * 2 + 0) * 256 + j4] = E;
    o4[(size_t)(bh * 2 + 1) * 256 + j4] = F;
}

// ---------------------------------------------------------------------------
// K3: MFMA contraction. [R2/R6-proven schedule, strictly simplified] 512
// blocks = (h-half, b, i-tile16); 4 waves, 1 head each.
//   A[i,j] = adj * max(Ei*Ej', Fi*Fj')  with Ej',Fj' PRE-normalized by 1/D
//   (k_nrm) — no ps loads, no divide chain in the superstep. Otherwise
//   byte-identical to the twice-passing schedule. No atomics, no setprio.
// ---------------------------------------------------------------------------
__global__ __launch_bounds__(256) void k_out_mfma(const float* __restrict__ adj,
                                                  const short* __restrict__ Gt,
                                                  const float* __restrict__ EFi,
                                                  const float* __restrict__ EFjtn,
                                                  float* __restrict__ out) {
    __shared__ short gts[4][4][32][40];  // 40KB: [h-local][jt-local][d][jj+pad]
    __shared__ float ejt[4][2][128];     // 4KB: [h-local][{E,F}/D][j in superstep]
    const int bx = blockIdx.x;
    const int hs = bx >> 8, b = (bx >> 6) & 3, i0 = (bx & 63) * 16;
    const int t = threadIdx.x;
    const int wave = t >> 6, lane = t & 63;
    const int m = lane & 15, q = lane >> 4;
    const int h = hs * 4 + wave;  // this wave's head

    const float2 eif = *(const float2*)&EFi[(size_t)(b * NN + i0 + m) * 16 + h * 2];
    const float EiV = eif.x, FiV = eif.y;
    f4v acc0 = {0.f, 0.f, 0.f, 0.f}, acc1 = {0.f, 0.f, 0.f, 0.f};

    const float* adjrow = adj + (size_t)b * NN * NN + (size_t)(i0 + m) * NN;
    const float4* gtg4 = (const float4*)Gt;  // 8 shorts per float4
    const float4* ejt4 = (const float4*)(EFjtn + (size_t)b * 8 * 2 * NN);

    for (int s = 0; s < 8; ++s) {
        // ---- issue Gt loads (named regs g0..g7) + adj loads (a0..a7) + ej
        float4 g0, g1, g2, g3, g4, g5, g6, g7;
#define LG(k)                                                                     \
        {                                                                         \
            const int u = t + 256 * (k);                                          \
            g##k = gtg4[(size_t)(b * 8 + hs * 4 + (u >> 9)) * 4096 + s * 512 +    \
                        (u & 511)];                                               \
        }
        LG(0) LG(1) LG(2) LG(3) LG(4) LG(5) LG(6) LG(7)
#undef LG
        f4v a0, a1, a2, a3, a4, a5, a6, a7;
#define LA(k2, lt, half)                                                          \
        a##k2 = *(const f4v*)&adjrow[s * 128 + (lt) * 32 + q * 8 + (half) * 4];
        LA(0, 0, 0) LA(1, 0, 1) LA(2, 1, 0) LA(3, 1, 1)
        LA(4, 2, 0) LA(5, 2, 1) LA(6, 3, 0) LA(7, 3, 1)
#undef LA
        // all 256 threads: one float4 of EFjtn ({E,F} rows x 4 heads x 32 f4),
        // already scaled by the per-(j,h) softmax denominator.
        const float4 ev =
            ejt4[(size_t)((hs * 4 + (t >> 6)) * 2 + ((t >> 5) & 1)) * 256 +
                 s * 32 + (t & 31)];
        __syncthreads();  // prior super's LDS reads done
#define SG(k)                                                                     \
        {                                                                         \
            const int u = t + 256 * (k);                                          \
            char* dstp = (char*)gts + (u >> 9) * 10240 + ((u >> 7) & 3) * 2560 +  \
                         ((u >> 2) & 31) * 80 + (u & 3) * 16;                     \
            *(float4*)dstp = g##k;                                                \
        }
        SG(0) SG(1) SG(2) SG(3) SG(4) SG(5) SG(6) SG(7)
#undef SG
        *(float4*)&ejt[t >> 6][(t >> 5) & 1][(t & 31) * 4] = ev;
        __syncthreads();  // LDS tile visible

        // ---- compute: 4 j-steps of 32, A built in named regs only
#define LT(lt, aA, aB)                                                            \
        {                                                                         \
            const f4v ejA = *(const f4v*)&ejt[wave][0][(lt) * 32 + q * 8];        \
            const f4v ejB = *(const f4v*)&ejt[wave][0][(lt) * 32 + q * 8 + 4];    \
            const f4v fjA = *(const f4v*)&ejt[wave][1][(lt) * 32 + q * 8];        \
            const f4v fjB = *(const f4v*)&ejt[wave][1][(lt) * 32 + q * 8 + 4];    \
            const float p0 = aA[0] * fmaxf(EiV * ejA[0], FiV * fjA[0]);           \
            const float p1 = aA[1] * fmaxf(EiV * ejA[1], FiV * fjA[1]);           \
            const float p2 = aA[2] * fmaxf(EiV * ejA[2], FiV * fjA[2]);           \
            const float p3 = aA[3] * fmaxf(EiV * ejA[3], FiV * fjA[3]);           \
            const float p4 = aB[0] * fmaxf(EiV * ejB[0], FiV * fjB[0]);           \
            const float p5 = aB[1] * fmaxf(EiV * ejB[1], FiV * fjB[1]);           \
            const float p6 = aB[2] * fmaxf(EiV * ejB[2], FiV * fjB[2]);           \
            const float p7 = aB[3] * fmaxf(EiV * ejB[3], FiV * fjB[3]);           \
            unsigned w0, w1, w2, w3;                                              \
            asm("v_cvt_pk_bf16_f32 %0, %1, %2" : "=v"(w0) : "v"(p0), "v"(p1));    \
            asm("v_cvt_pk_bf16_f32 %0, %1, %2" : "=v"(w1) : "v"(p2), "v"(p3));    \
            asm("v_cvt_pk_bf16_f32 %0, %1, %2" : "=v"(w2) : "v"(p4), "v"(p5));    \
            asm("v_cvt_pk_bf16_f32 %0, %1, %2" : "=v"(w3) : "v"(p6), "v"(p7));    \
            union { unsigned u[4]; s8v v; } Au;                                   \
            Au.u[0] = w0; Au.u[1] = w1; Au.u[2] = w2; Au.u[3] = w3;               \
            const s8v A = Au.v;                                                   \
            const s8v B0 = *(const s8v*)&gts[wave][lt][m][q * 8];                 \
            const s8v B1 = *(const s8v*)&gts[wave][lt][m + 16][q * 8];            \
            acc0 = __builtin_amdgcn_mfma_f32_16x16x32_bf16(A, B0, acc0, 0, 0, 0); \
            acc1 = __builtin_amdgcn_mfma_f32_16x16x32_bf16(A, B1, acc1, 0, 0, 0); \
        }
        LT(0, a0, a1) LT(1, a2, a3) LT(2, a4, a5) LT(3, a6, a7)
#undef LT
    }

    // ---- epilogue: C layout col=lane&15, row=quad*4+reg (already normalized)
    float* op = out + (size_t)(b * NN + i0) * 256;
#pragma unroll
    for (int r = 0; r < 4; ++r) {
        const int row = q * 4 + r;
        op[(size_t)row * 256 + h * 32 + m] = acc0[r];
        op[(size_t)row * 256 + h * 32 + 16 + m] = acc1[r];
    }
}

// ---------------------------------------------------------------------------
extern "C" void kernel_launch(void* const* d_in, const int* in_sizes, int n_in,
                              void* d_out, int out_size, void* d_ws, size_t ws_size,
                              hipStream_t stream) {
    const float* h      = (const float*)d_in[0];  // [4,1024,256]
    const float* adj    = (const float*)d_in[1];  // [4,1024,1024,1]
    const float* W      = (const float*)d_in[2];  // [256,256]
    const float* attn_w = (const float*)d_in[3];  // [64]
    float* out = (float*)d_out;                   // [4,1024,256]

    float* ws = (float*)d_ws;
    short* Gt    = (short*)ws;              // 2MB used (4MB slot = 1,048,576 f)
    float* EFi   = ws + 1048576;            // 65,536 f
    float* EFjt  = EFi + NROW * 16;         // 65,536 f  [b][h][{E,F}][n]  (raw)
    float* ps    = EFjt + NROW * 16;        // 262,144 f [ic][b][h][j]
    float* EFjtn = ps + 8 * NROW * 8;       // 65,536 f  [b][h][{E,F}][n] (/D)

    k_gemm_ei<<<NROW / 8, 256, 0, stream>>>(h, W, attn_w, Gt, EFi, EFjt);
    k_s<<<512, 256, 0, stream>>>(adj, EFi, EFjt, ps);
    k_nrm<<<32, 256, 0, stream>>>(ps, EFjt, EFjtn);
    k_out_mfma<<<512, 256, 0, stream>>>(adj, Gt, EFi, EFjtn, out);
}